// Round 6
// baseline (644.440 us; speedup 1.0000x reference)
//
#include <hip/hip_runtime.h>

// CTC loss forward, T=1024, B=128, C=256, S=128, L=2S+1=257.
// R2-R5 lesson: single-wave register prefetch keeps getting re-sunk by LLVM
// (VGPR 36-48, MLP~3) -> ~300 cyc/step exposed HBM latency, 170 us plateau.
// This version makes prefetch a SEPARATE WAVE's program: 128 threads/block,
// wave 1 = producer (global gather -> exp2 -> LDS), wave 0 = consumer (f64
// recursion off LDS), double-buffered 16-step chunks, __syncthreads per chunk.
// Producer load latency (~600 cyc/chunk) hides under consumer compute
// (~1500+ cyc/chunk). Producer also pre-computes exp2f(lp*log2e + 9), so the
// consumer step is pure f64 math + 3 LDS reads.
// LDS layout [type][d][lane]: both ds_write and ds_read are lane-contiguous
// (conflict-free). FP64 exp-domain states (708-nat range), 2^9 bias per step,
// exact power-of-2 wave renorm every chunk (16 steps).

#define PF 16                 // steps per chunk
#define CTC_C 256
#define EXP_BIAS 9.0f         // each prob scaled by 2^9 inside exp2
#define LOG2E 1.4426950408889634f
#define LN2 0.6931471805599453

__global__ __launch_bounds__(128, 1)
void ctc_fwd(const float* __restrict__ lp, const int* __restrict__ y,
             const int* __restrict__ ilen, const int* __restrict__ tlen,
             float* __restrict__ out, int T, int B, int S) {
  const int b = blockIdx.x;
  const int tid = threadIdx.x;
  const int l = tid & 63;               // lane within wave
  const int wid = tid >> 6;             // 0 = consumer, 1 = producer
  const size_t rowstride = (size_t)B * CTC_C;

  // chunk buffers: [buf][type(A,B,Q)][d][lane]
  __shared__ float trans[2][3 * PF * 64];

  const int len = ilen[b];
  const int tl  = tlen[b];
  const int nsteps = len - 1;                   // steps t = 1..nsteps
  const int NC = (nsteps + PF - 1) / PF;        // chunks

  const int ya = y[(size_t)b * S + 2 * l];
  const int yb = y[(size_t)b * S + 2 * l + 1];
  const int yprev = __shfl_up(yb, 1);           // y[2l-1]; garbage on lane 0
  const double maskA = (ya != yprev) ? 1.0 : 0.0;  // lane0 ok: its Opm1 is 0
  const double maskB = (yb != ya) ? 1.0 : 0.0;

  // consumer state (wave 0); harmless on wave 1
  const float* row0 = lp + (size_t)b * CTC_C;
  const int y0 = y[(size_t)b * S];
  double Ea = (l == 0) ? (double)__expf(row0[0])  : 0.0;  // E[2l]
  double Oa = (l == 0) ? (double)__expf(row0[y0]) : 0.0;  // O[2l]
  double Eb = 0.0, Ob = 0.0, E128 = 0.0;
  double Opm1 = 0.0;
  int e_sum = 0;

  // producer pointer state (wave 1): row walk, clamped at T-1
  const float* rQ = lp + rowstride + (size_t)b * CTC_C;   // row 1, blank col
  const float* rA = rQ + ya;
  const float* rB = rQ + yb;
  int rrow = 1;

  auto produce = [&](int cc) {
    float vA[PF], vB[PF], vQ[PF];
#pragma unroll
    for (int d = 0; d < PF; ++d) {
      vA[d] = *rA; vB[d] = *rB; vQ[d] = *rQ;
      if (rrow + 1 < T) { rA += rowstride; rB += rowstride; rQ += rowstride; ++rrow; }
    }
    float* dst = &trans[cc & 1][l];
#pragma unroll
    for (int d = 0; d < PF; ++d) {
      dst[(0 * PF + d) * 64] = exp2f(fmaf(vA[d], LOG2E, EXP_BIAS));
      dst[(1 * PF + d) * 64] = exp2f(fmaf(vB[d], LOG2E, EXP_BIAS));
      dst[(2 * PF + d) * 64] = exp2f(fmaf(vQ[d], LOG2E, EXP_BIAS));
    }
  };

#define STEP(AV, BV, QV) do {                                   \
    const double pa = (double)(AV);                             \
    const double pb = (double)(BV);                             \
    const double pq = (double)(QV);                             \
    double nOb = fma(maskB, Oa, Ob + Eb) * pb;                  \
    double up = __shfl_up(nOb, 1);                              \
    double nOa = fma(maskA, Opm1, Oa + Ea) * pa;                \
    double nEa = (Ea + Opm1) * pq;                              \
    double nEb = (Eb + Oa) * pq;                                \
    E128 = (E128 + Ob) * pq;                                    \
    Oa = nOa; Ob = nOb; Ea = nEa; Eb = nEb;                     \
    Opm1 = (l == 0) ? 0.0 : up;                                 \
  } while (0)

  // prologue: stage chunk 0
  if (wid == 1) produce(0);
  __syncthreads();

  for (int c = 0; c < NC; ++c) {
    if (wid == 1) {
      if (c + 1 < NC) produce(c + 1);           // into trans[(c+1)&1]
    } else {
      const float* src = &trans[c & 1][l];
      float fA[PF], fB[PF], fQ[PF];
#pragma unroll
      for (int d = 0; d < PF; ++d) {
        fA[d] = src[(0 * PF + d) * 64];
        fB[d] = src[(1 * PF + d) * 64];
        fQ[d] = src[(2 * PF + d) * 64];
      }
      const int rem = nsteps - c * PF;          // wave-uniform
      if (rem >= PF) {
#pragma unroll
        for (int d = 0; d < PF; ++d) STEP(fA[d], fB[d], fQ[d]);
        // renorm every chunk (16 steps): exact power-of-2 wave rescale
        double m = fmax(fmax(Oa, Ob), fmax(Ea, Eb));
        m = fmax(m, E128);
#pragma unroll
        for (int off = 32; off > 0; off >>= 1)
          m = fmax(m, __shfl_xor(m, off));
        long long bits = __double_as_longlong(m);
        int eb2 = (int)((bits >> 52) & 0x7ff);
        int e = eb2 - 1022;                     // m = f*2^e, f in [0.5,1)
        double s = __longlong_as_double((long long)(2045 - eb2) << 52); // 2^-e
        Oa *= s; Ob *= s; Ea *= s; Eb *= s; E128 *= s; Opm1 *= s;
        e_sum += e;
      } else {
#pragma unroll
        for (int d = 0; d < PF; ++d)
          if (d < rem) STEP(fA[d], fB[d], fQ[d]);
      }
    }
    __syncthreads();
  }

  if (wid == 0) {
    // readout: true alpha = stored * 2^(e_sum - 9*nsteps)
    E128 = __shfl(E128, 63);                    // the real E[128]
    double vEa = __shfl(Ea, (tl >> 1) & 63);
    double vEb = __shfl(Eb, (tl >> 1) & 63);
    double vhi = (tl == S) ? E128 : ((tl & 1) ? vEb : vEa);   // alpha[2*tl]
    const int s2 = tl - 1;
    double vOa = __shfl(Oa, (s2 >> 1) & 63);
    double vOb = __shfl(Ob, (s2 >> 1) & 63);
    double vlo = (s2 & 1) ? vOb : vOa;                        // alpha[2*tl-1]

    double sum = vhi + vlo;
    double loss;
    if (sum > 0.0) {
      double ll = log(sum) + (double)(e_sum - 9 * nsteps) * LN2;
      loss = -ll;
    } else {
      loss = 1e30;                              // -inf likelihood
    }
    if (!(loss < 5.0e8)) loss = 0.0;            // zero_infinity (inf/NaN too)
    float contrib = (float)(loss / (double)tl / (double)B);
    if (l == 0) atomicAdd(out, contrib);
  }
}

extern "C" void kernel_launch(void* const* d_in, const int* in_sizes, int n_in,
                              void* d_out, int out_size, void* d_ws, size_t ws_size,
                              hipStream_t stream) {
  const float* lp   = (const float*)d_in[0];
  const int*   yy   = (const int*)d_in[1];
  const int*   ilen = (const int*)d_in[2];
  const int*   tlen = (const int*)d_in[3];
  float* out = (float*)d_out;

  int B = in_sizes[2];
  int S = in_sizes[1] / B;
  int T = in_sizes[0] / (B * CTC_C);

  hipMemsetAsync(out, 0, sizeof(float), stream);
  ctc_fwd<<<B, 128, 0, stream>>>(lp, yy, ilen, tlen, out, T, B, S);
}

// Round 7
// 305.623 us; speedup vs baseline: 2.1086x; 2.1086x over previous
//
#include <hip/hip_runtime.h>

// CTC loss forward, T=1024, B=128, C=256, S=128, L=2S+1=257.
// One wave per batch; lane l owns O[2l],O[2l+1] (labels y[2l],y[2l+1]) and
// blanks E[2l],E[2l+1]; E[128] is a per-lane sink (real on lane 63). FP64
// exp-domain states (708-nat range), 2^9 bias folded into exp2, exact
// power-of-2 wave renorm every 16-step chunk.
//
// R3-R6 lesson: any prefetch that produces REGISTER results gets sunk to its
// uses by LLVM (MLP~1-3, ~300-400 cyc/step exposed HBM latency; R6's
// producer wave ran 48 loads/chunk fully serialized = 19k cyc/chunk).
// Fix: __builtin_amdgcn_global_load_lds -- global->LDS DMA with NO register
// result, so there is nothing to sink. Per-lane global address = a 64-wide
// gather per instruction; LDS dest = uniform base + lane*4 (contiguous,
// conflict-free). Issue all 48 DMAs for chunk c+1, compute chunk c off LDS,
// then __syncthreads() (compiler ends it with s_waitcnt vmcnt(0) -- the m97
// staging pattern), giving the DMA a full chunk of compute to land.

#define PF 16                 // steps per chunk
#define CTC_C 256
#define EXP_BIAS 9.0f         // each prob scaled by 2^9 inside exp2
#define LOG2E 1.4426950408889634f
#define LN2 0.6931471805599453

__device__ __forceinline__ void gl_lds(const float* g, float* s) {
  __builtin_amdgcn_global_load_lds(
      (const __attribute__((address_space(1))) unsigned int*)g,
      (__attribute__((address_space(3))) unsigned int*)s, 4, 0, 0);
}

__global__ __launch_bounds__(64, 1)
void ctc_fwd(const float* __restrict__ lp, const int* __restrict__ y,
             const int* __restrict__ ilen, const int* __restrict__ tlen,
             float* __restrict__ out, int T, int B, int S) {
  const int b = blockIdx.x;
  const int l = threadIdx.x;            // 0..63
  const size_t rowstride = (size_t)B * CTC_C;

  // [buf][type(A,B,Q)][d][lane]
  __shared__ float buf[2][3 * PF * 64];

  const int len = ilen[b];
  const int tl  = tlen[b];
  const int nsteps = len - 1;                   // steps t = 1..nsteps
  const int NC = (nsteps + PF - 1) / PF;        // chunks

  const int ya = y[(size_t)b * S + 2 * l];
  const int yb = y[(size_t)b * S + 2 * l + 1];
  const int yprev = __shfl_up(yb, 1);           // y[2l-1]; garbage on lane 0
  const double maskA = (ya != yprev) ? 1.0 : 0.0;  // lane0 ok: its Opm1 is 0
  const double maskB = (yb != ya) ? 1.0 : 0.0;

  // t=0 init: alpha[0]=exp(lp0[blank]) -> E[0]; alpha[1]=exp(lp0[y0]) -> O[0]
  const float* row0 = lp + (size_t)b * CTC_C;
  const int y0 = y[(size_t)b * S];
  double Ea = (l == 0) ? (double)__expf(row0[0])  : 0.0;
  double Oa = (l == 0) ? (double)__expf(row0[y0]) : 0.0;
  double Eb = 0.0, Ob = 0.0, E128 = 0.0;
  double Opm1 = 0.0;
  int e_sum = 0;

  // gather pointers: per-lane rA/rB, uniform rQ; uniform row walk clamped T-1
  const float* rQ = lp + rowstride + (size_t)b * CTC_C;   // row 1, blank col
  const float* rA = rQ + ya;
  const float* rB = rQ + yb;
  int rrow = 1;

  auto stage = [&](int cc) {            // issue 48 DMAs for chunk cc
    float* base = &buf[cc & 1][0];
#pragma unroll
    for (int d = 0; d < PF; ++d) {
      gl_lds(rA, base + (0 * PF + d) * 64);
      gl_lds(rB, base + (1 * PF + d) * 64);
      gl_lds(rQ, base + (2 * PF + d) * 64);
      if (rrow + 1 < T) { rA += rowstride; rB += rowstride; rQ += rowstride; ++rrow; }
    }
  };

#define STEP(AV, BV, QV) do {                                   \
    const double pa = (double)exp2f(fmaf((AV), LOG2E, EXP_BIAS)); \
    const double pb = (double)exp2f(fmaf((BV), LOG2E, EXP_BIAS)); \
    const double pq = (double)exp2f(fmaf((QV), LOG2E, EXP_BIAS)); \
    double nOb = fma(maskB, Oa, Ob + Eb) * pb;                  \
    double up = __shfl_up(nOb, 1);                              \
    double nOa = fma(maskA, Opm1, Oa + Ea) * pa;                \
    double nEa = (Ea + Opm1) * pq;                              \
    double nEb = (Eb + Oa) * pq;                                \
    E128 = (E128 + Ob) * pq;                                    \
    Oa = nOa; Ob = nOb; Ea = nEa; Eb = nEb;                     \
    Opm1 = (l == 0) ? 0.0 : up;                                 \
  } while (0)

  stage(0);
  __syncthreads();                      // vmcnt(0): chunk 0 landed

  for (int c = 0; c < NC; ++c) {
    if (c + 1 < NC) stage(c + 1);       // DMAs fly during this chunk's math

    const float* src = &buf[c & 1][l];
    const int rem = nsteps - c * PF;    // wave-uniform
    if (rem >= PF) {
      // 1-step lookahead on the LDS reads to keep ds latency off the path
      float a0 = src[(0 * PF) * 64], b0 = src[(1 * PF) * 64], q0 = src[(2 * PF) * 64];
#pragma unroll
      for (int d = 0; d < PF; ++d) {
        float a1 = 0.f, b1 = 0.f, q1 = 0.f;
        if (d + 1 < PF) {
          a1 = src[(0 * PF + d + 1) * 64];
          b1 = src[(1 * PF + d + 1) * 64];
          q1 = src[(2 * PF + d + 1) * 64];
        }
        STEP(a0, b0, q0);
        a0 = a1; b0 = b1; q0 = q1;
      }
      // renorm every chunk (16 steps): exact power-of-2 wave rescale
      double m = fmax(fmax(Oa, Ob), fmax(Ea, Eb));
      m = fmax(m, E128);
#pragma unroll
      for (int off = 32; off > 0; off >>= 1)
        m = fmax(m, __shfl_xor(m, off));
      long long bits = __double_as_longlong(m);
      int eb2 = (int)((bits >> 52) & 0x7ff);
      int e = eb2 - 1022;               // m = f*2^e, f in [0.5,1)
      double s = __longlong_as_double((long long)(2045 - eb2) << 52); // 2^-e
      Oa *= s; Ob *= s; Ea *= s; Eb *= s; E128 *= s; Opm1 *= s;
      e_sum += e;
    } else {
#pragma unroll
      for (int d = 0; d < PF; ++d) {
        if (d < rem) {                  // wave-uniform predicate
          float av = src[(0 * PF + d) * 64];
          float bv = src[(1 * PF + d) * 64];
          float qv = src[(2 * PF + d) * 64];
          STEP(av, bv, qv);
        }
      }
    }
    __syncthreads();                    // vmcnt(0): chunk c+1 landed
  }

  // readout: true alpha = stored * 2^(e_sum - 9*nsteps)
  E128 = __shfl(E128, 63);                    // the real E[128]
  double vEa = __shfl(Ea, (tl >> 1) & 63);
  double vEb = __shfl(Eb, (tl >> 1) & 63);
  double vhi = (tl == S) ? E128 : ((tl & 1) ? vEb : vEa);   // alpha[2*tl]
  const int s2 = tl - 1;
  double vOa = __shfl(Oa, (s2 >> 1) & 63);
  double vOb = __shfl(Ob, (s2 >> 1) & 63);
  double vlo = (s2 & 1) ? vOb : vOa;                        // alpha[2*tl-1]

  double sum = vhi + vlo;
  double loss;
  if (sum > 0.0) {
    double ll = log(sum) + (double)(e_sum - 9 * nsteps) * LN2;
    loss = -ll;
  } else {
    loss = 1e30;                              // -inf likelihood
  }
  if (!(loss < 5.0e8)) loss = 0.0;            // zero_infinity (inf/NaN too)
  float contrib = (float)(loss / (double)tl / (double)B);
  if (l == 0) atomicAdd(out, contrib);
}

extern "C" void kernel_launch(void* const* d_in, const int* in_sizes, int n_in,
                              void* d_out, int out_size, void* d_ws, size_t ws_size,
                              hipStream_t stream) {
  const float* lp   = (const float*)d_in[0];
  const int*   yy   = (const int*)d_in[1];
  const int*   ilen = (const int*)d_in[2];
  const int*   tlen = (const int*)d_in[3];
  float* out = (float*)d_out;

  int B = in_sizes[2];
  int S = in_sizes[1] / B;
  int T = in_sizes[0] / (B * CTC_C);

  hipMemsetAsync(out, 0, sizeof(float), stream);
  ctc_fwd<<<B, 64, 0, stream>>>(lp, yy, ilen, tlen, out, T, B, S);
}